// Round 11
// baseline (1162.969 us; speedup 1.0000x reference)
//
#include <hip/hip_runtime.h>
#include <hip/hip_bf16.h>

#define B_N   32768
#define HID   512
#define DIM   256
#define MAXN  17
#define SM    264   // SP_MID == KEY_MID
#define DM    384   // DEC_MID

typedef __attribute__((ext_vector_type(8))) short bf16x8;
typedef __attribute__((ext_vector_type(4))) float f32x4;

#define AS1 __attribute__((address_space(1)))
#define AS3 __attribute__((address_space(3)))

static __device__ __forceinline__ unsigned short f2bf(float x) {
  union { float f; unsigned u; } v; v.f = x;
  unsigned r = (v.u + 0x7FFFu + ((v.u >> 16) & 1u)) >> 16;   // RNE
  return (unsigned short)r;
}

// Packed RNE f32x2 -> bf16x2 (v_cvt_pk_bf16_f32); bit-identical to f2bf pair.
static __device__ __forceinline__ unsigned pkbf(float a, float b) {
  __hip_bfloat162 h = __float22bfloat162_rn(float2{a, b});
  union { __hip_bfloat162 h; unsigned u; } cv; cv.h = h;
  return cv.u;
}

// ---------------------------------------------------------------------------
// Stage 1: size_pred MLP + argmax.  16 samples / workgroup, 320 threads.
// v6 (verbatim from passing round-6): all staging via global_load_lds.
// MUST stay fp32: argmax flips would corrupt the ragged layout.
// ---------------------------------------------------------------------------
__global__ __launch_bounds__(320, 3) void sizepred_kernel(
    const float* __restrict__ z,  const float* __restrict__ W1,
    const float* __restrict__ b1, const float* __restrict__ g1,
    const float* __restrict__ be1, const float* __restrict__ W2,
    const float* __restrict__ b2, int* __restrict__ n_out)
{
  // pool: zs[16][516] (33024 B, aliased by us[16][268]) + wbuf[2] (8448 B each)
  __shared__ __align__(16) char smem[33024 + 2 * 8448];
  float* zs  = (float*)smem;
  float* us  = (float*)smem;
  float* wb0 = (float*)(smem + 33024);
  float* wb1 = (float*)(smem + 33024 + 8448);
  __shared__ float lnm[16], lnr[16];
  __shared__ float log17[16 * 17];

  const int tid = threadIdx.x;
  const int b0  = blockIdx.x * 16;
  const int wv  = tid >> 6;     // wave 0..4
  const int ln  = tid & 63;

  const bool act = tid < 264;
  const int  s0  = (tid / 66) * 4;
  const int  j0  = (tid % 66) * 4;

  float acc[4][4];
#pragma unroll
  for (int i = 0; i < 4; ++i)
#pragma unroll
    for (int q = 0; q < 4; ++q) acc[i][q] = 0.f;

  // ---- stage zs (once): 16 rows x 512 f = 32 slices of 64 float4.
  for (int s = wv; s < 32; s += 5) {
    int r = s >> 1, sl = s & 1;
    const float* gp = z + (size_t)(b0 + r) * 512 + sl * 256 + ln * 4;
    __builtin_amdgcn_global_load_lds(
        (const AS1 unsigned*)gp,
        (AS3 unsigned*)(zs + r * 516 + sl * 256), 16, 0, 0);
  }
  // ---- stage W chunk 0 into wb0: 528 f4 = 8 full slices + 64-float tail ----
  {
    const float* gc = W1;
    const float* gp1 = gc + (size_t)(wv * 64 + ln) * 4;
    __builtin_amdgcn_global_load_lds(
        (const AS1 unsigned*)gp1, (AS3 unsigned*)(wb0 + wv * 256), 16, 0, 0);
    if (wv < 3) {
      const float* gp2 = gc + (size_t)((wv + 5) * 64 + ln) * 4;
      __builtin_amdgcn_global_load_lds(
          (const AS1 unsigned*)gp2, (AS3 unsigned*)(wb0 + (wv + 5) * 256), 16, 0, 0);
    } else if (wv == 3) {
      const float* gp2 = gc + 2048 + ln;     // floats 2048..2111 (width 4)
      __builtin_amdgcn_global_load_lds(
          (const AS1 unsigned*)gp2, (AS3 unsigned*)(wb0 + 2048), 4, 0, 0);
    }
  }
  __syncthreads();

  // ---- main GEMM: 64 chunks of 8 k, double-buffered W1 via global_load_lds ----
  float* cw = wb0;
  float* nw = wb1;
#pragma unroll 1
  for (int ch = 0; ch < 64; ++ch) {
    if (ch + 1 < 64) {
      const float* gc = W1 + (size_t)(ch + 1) * 2112;   // 8*264
      const float* gp1 = gc + (size_t)(wv * 64 + ln) * 4;
      __builtin_amdgcn_global_load_lds(
          (const AS1 unsigned*)gp1, (AS3 unsigned*)(nw + wv * 256), 16, 0, 0);
      if (wv < 3) {
        const float* gp2 = gc + (size_t)((wv + 5) * 64 + ln) * 4;
        __builtin_amdgcn_global_load_lds(
            (const AS1 unsigned*)gp2, (AS3 unsigned*)(nw + (wv + 5) * 256), 16, 0, 0);
      } else if (wv == 3) {
        const float* gp2 = gc + 2048 + ln;
        __builtin_amdgcn_global_load_lds(
            (const AS1 unsigned*)gp2, (AS3 unsigned*)(nw + 2048), 4, 0, 0);
      }
    }
    if (act) {
      const int zb = ch * 8;
#pragma unroll
      for (int u = 0; u < 2; ++u) {
        float4 za0 = *(const float4*)&zs[(s0 + 0) * 516 + zb + u * 4];
        float4 za1 = *(const float4*)&zs[(s0 + 1) * 516 + zb + u * 4];
        float4 za2 = *(const float4*)&zs[(s0 + 2) * 516 + zb + u * 4];
        float4 za3 = *(const float4*)&zs[(s0 + 3) * 516 + zb + u * 4];
#pragma unroll
        for (int e = 0; e < 4; ++e) {
          float4 w = *(const float4*)&cw[(u * 4 + e) * 264 + j0];
          float a0 = (e == 0) ? za0.x : (e == 1) ? za0.y : (e == 2) ? za0.z : za0.w;
          float a1 = (e == 0) ? za1.x : (e == 1) ? za1.y : (e == 2) ? za1.z : za1.w;
          float a2 = (e == 0) ? za2.x : (e == 1) ? za2.y : (e == 2) ? za2.z : za2.w;
          float a3 = (e == 0) ? za3.x : (e == 1) ? za3.y : (e == 2) ? za3.z : za3.w;
          acc[0][0] += a0 * w.x; acc[0][1] += a0 * w.y; acc[0][2] += a0 * w.z; acc[0][3] += a0 * w.w;
          acc[1][0] += a1 * w.x; acc[1][1] += a1 * w.y; acc[1][2] += a1 * w.z; acc[1][3] += a1 * w.w;
          acc[2][0] += a2 * w.x; acc[2][1] += a2 * w.y; acc[2][2] += a2 * w.z; acc[2][3] += a2 * w.w;
          acc[3][0] += a3 * w.x; acc[3][1] += a3 * w.y; acc[3][2] += a3 * w.z; acc[3][3] += a3 * w.w;
        }
      }
    }
    float* t = cw; cw = nw; nw = t;
    __syncthreads();
  }

  // ---- bias into registers (masked), uniform barrier, masked store ----
  float4 o0, o1, o2, o3;
  if (act) {
    float4 bb = *(const float4*)&b1[j0];
    o0.x = acc[0][0] + bb.x; o0.y = acc[0][1] + bb.y; o0.z = acc[0][2] + bb.z; o0.w = acc[0][3] + bb.w;
    o1.x = acc[1][0] + bb.x; o1.y = acc[1][1] + bb.y; o1.z = acc[1][2] + bb.z; o1.w = acc[1][3] + bb.w;
    o2.x = acc[2][0] + bb.x; o2.y = acc[2][1] + bb.y; o2.z = acc[2][2] + bb.z; o2.w = acc[2][3] + bb.w;
    o3.x = acc[3][0] + bb.x; o3.y = acc[3][1] + bb.y; o3.z = acc[3][2] + bb.z; o3.w = acc[3][3] + bb.w;
  }
  __syncthreads();   // zs -> us handoff (uniform: all zs reads done above)
  if (act) {
    *(float4*)&us[(s0 + 0) * 268 + j0] = o0;
    *(float4*)&us[(s0 + 1) * 268 + j0] = o1;
    *(float4*)&us[(s0 + 2) * 268 + j0] = o2;
    *(float4*)&us[(s0 + 3) * 268 + j0] = o3;
  }
  __syncthreads();

  // LN stats: serial per sample — EXACT summation order of verified baseline.
  if (tid < 16) {
    float s = 0.f, q = 0.f;
    for (int j = 0; j < 264; ++j) { float v = us[tid * 268 + j]; s += v; q += v * v; }
    float m   = s / 264.f;
    float var = q / 264.f - m * m;
    lnm[tid] = m;
    lnr[tid] = 1.f / sqrtf(var + 1e-5f);
  }
  __syncthreads();

  for (int idx = tid; idx < 16 * 264; idx += 320) {
    int s = idx / 264, j = idx - s * 264;
    float v = (us[s * 268 + j] - lnm[s]) * lnr[s] * g1[j] + be1[j];
    us[s * 268 + j] = fmaxf(v, 0.f);
  }
  __syncthreads();

  if (tid < 272) {
    int s = tid / 17, jj = tid - s * 17;
    float a = b2[jj];
    const float* up = &us[s * 268];
#pragma unroll 4
    for (int c = 0; c < 264; c += 4) {
      float4 u = *(const float4*)(up + c);
      a += u.x * W2[(c + 0) * 17 + jj];
      a += u.y * W2[(c + 1) * 17 + jj];
      a += u.z * W2[(c + 2) * 17 + jj];
      a += u.w * W2[(c + 3) * 17 + jj];
    }
    log17[tid] = a;
  }
  __syncthreads();

  if (tid < 16) {
    int best = 0; float bv = log17[tid * 17];
    for (int jj = 1; jj < 17; ++jj) {
      float v = log17[tid * 17 + jj];
      if (v > bv) { bv = v; best = jj; }
    }
    n_out[b0 + tid] = best;
  }
}

// ---------------------------------------------------------------------------
// Stage 2: exclusive prefix sum of n[32768] -> starts[32769]. One block.
// ---------------------------------------------------------------------------
__global__ __launch_bounds__(1024) void scan_kernel(const int* __restrict__ n,
                                                    int* __restrict__ starts)
{
  __shared__ int part[1024];
  const int tid  = threadIdx.x;
  const int base = tid * 32;
  int loc[32];
  int s = 0;
#pragma unroll
  for (int i = 0; i < 8; ++i) {
    int4 v = ((const int4*)(n + base))[i];
    loc[i * 4 + 0] = v.x; loc[i * 4 + 1] = v.y;
    loc[i * 4 + 2] = v.z; loc[i * 4 + 3] = v.w;
    s += v.x + v.y + v.z + v.w;
  }
  part[tid] = s;
  __syncthreads();
  for (int off = 1; off < 1024; off <<= 1) {
    int v   = part[tid];
    int add = (tid >= off) ? part[tid - off] : 0;
    __syncthreads();
    part[tid] = v + add;
    __syncthreads();
  }
  int run = part[tid] - s;
#pragma unroll
  for (int i = 0; i < 8; ++i) {
    int4 w;
    w.x = run; run += loc[i * 4 + 0];
    w.y = run; run += loc[i * 4 + 1];
    w.z = run; run += loc[i * 4 + 2];
    w.w = run; run += loc[i * 4 + 3];
    ((int4*)(starts + base))[i] = w;
  }
  if (tid == 1023) starts[B_N] = run;
}

// ---------------------------------------------------------------------------
// Stage 3: scatter ragged indices + write batch output (as float)
// ---------------------------------------------------------------------------
__global__ __launch_bounds__(256) void scatter_kernel(
    const int* __restrict__ n, const int* __restrict__ starts,
    int* __restrict__ bi, int* __restrict__ ki, float* __restrict__ out, int T)
{
  int b = blockIdx.x * 256 + threadIdx.x;
  if (b >= B_N) return;
  int st = starts[b], nn = n[b];
  float* ob = out + (size_t)T * DIM;
  for (int k = 0; k < nn; ++k) {
    bi[st + k] = b;
    ki[st + k] = k;
    ob[st + k] = (float)b;
  }
}

// ---------------------------------------------------------------------------
// Stage 4: keys table [17][512]
// ---------------------------------------------------------------------------
__global__ __launch_bounds__(320) void keys_kernel(
    const float* __restrict__ W1, const float* __restrict__ b1,
    const float* __restrict__ g1, const float* __restrict__ be1,
    const float* __restrict__ W2, const float* __restrict__ b2,
    float* __restrict__ ktab)
{
  __shared__ float hs[264];
  __shared__ float mr[2];
  const int kk = blockIdx.x, tid = threadIdx.x;
  if (tid < 264) hs[tid] = W1[kk * 264 + tid] + b1[tid];
  __syncthreads();
  if (tid == 0) {
    float s = 0.f, q = 0.f;
    for (int j = 0; j < 264; ++j) { float v = hs[j]; s += v; q += v * v; }
    float m = s / 264.f;
    mr[0] = m;
    mr[1] = 1.f / sqrtf(q / 264.f - m * m + 1e-5f);
  }
  __syncthreads();
  if (tid < 264) hs[tid] = fmaxf((hs[tid] - mr[0]) * mr[1] * g1[tid] + be1[tid], 0.f);
  __syncthreads();
  for (int c = tid; c < 512; c += 320) {
    float a = b2[c];
    for (int j = 0; j < 264; ++j) a += hs[j] * W2[j * 512 + c];
    ktab[kk * 512 + c] = a;
  }
}

// ---------------------------------------------------------------------------
// Stage 4b: pack dec_W1/dec_W2 into bf16 MFMA B-fragment layout.
// Chunk (kt, nt, lane): 8 bf16 = W[kt*32 + (lane>>4)*8 + j][nt*16 + (lane&15)]
// W1p: 16 kt x 24 nt ; W2p: 12 kt x 16 nt.  grid 576 x 64.
// ---------------------------------------------------------------------------
__global__ __launch_bounds__(64) void pack_kernel(
    const float* __restrict__ W1, const float* __restrict__ W2,
    short* __restrict__ W1p, short* __restrict__ W2p)
{
  const int g = blockIdx.x, l = threadIdx.x;
  const float* W; int nt, kt, N;
  if (g < 384) { W = W1; kt = g / 24; nt = g % 24; N = 384; }
  else         { W = W2; int gg = g - 384; kt = gg / 16; nt = gg % 16; N = 256; }
  const int krow = kt * 32 + ((l >> 4) << 3);
  const int col  = nt * 16 + (l & 15);
  short v[8];
#pragma unroll
  for (int j = 0; j < 8; ++j)
    v[j] = (short)f2bf(W[(size_t)(krow + j) * N + col]);
  short* d = (g < 384) ? (W1p + ((size_t)g * 64 + l) * 8)
                       : (W2p + ((size_t)(g - 384) * 64 + l) * 8);
  *(bf16x8*)d = *(bf16x8*)v;
}

// ---------------------------------------------------------------------------
// Stage 5: MFMA decoder v4: 64 rows / block, 512 threads (8 waves,
// 2 row-halves x 4 col-slices).  Per-CU arithmetic at 32 rows/block showed
// an L2-BW floor of ~205us from B-fragment streaming (576KB/block); 64 rows
// halves per-row B traffic while KEEPING 16 waves/CU (2 blocks x 8 waves;
// LDS 64.5KB).  Per-wave work/VGPR identical to the verified 452us kernel.
// ---------------------------------------------------------------------------
__global__ __launch_bounds__(512, 4) void decoder_kernel(
    const float* __restrict__ z,  const float* __restrict__ ktab,
    const short* __restrict__ W1p, const float* __restrict__ b1,
    const short* __restrict__ W2p, const float* __restrict__ b2,
    const int* __restrict__ bi,   const int* __restrict__ ki,
    float* __restrict__ out, int T)
{
  // zps: 16 kt x 4 mtg x 64 lanes x 8 bf16 = 64 KB.  Hs (48 KB) aliases it.
  __shared__ __align__(16) short zps[32768];
  __shared__ int tb[64], tk[64];

  const int tid  = threadIdx.x;
  const int wave = tid >> 6;     // 0..7
  const int lane = tid & 63;
  const int wr   = wave >> 2;    // row half (0..1)
  const int wc   = wave & 3;     // col slice (0..3)
  const int t0   = blockIdx.x * 64;

  if (tid < 64) {
    int t = t0 + tid;
    tb[tid] = (t < T) ? bi[t] : 0;
    tk[tid] = (t < T) ? ki[t] : 0;
  }
  __syncthreads();

  // ---- stage zp = z[b]*ktab[k] into A-fragment layout ----
  // chunk = (kt*4 + mtg)*64 + lane ; elem j = zp[mtg*16+(lane&15)][kt*32+(lane>>4)*8+j]
#pragma unroll
  for (int it = 0; it < 8; ++it) {
    int chunk = tid + it * 512;
    int l   = chunk & 63;
    int mtg = (chunk >> 6) & 3;
    int kt  = chunk >> 8;
    int m   = mtg * 16 + (l & 15);
    int k0  = kt * 32 + ((l >> 4) << 3);
    const float4* zr = (const float4*)(z    + (size_t)tb[m] * 512 + k0);
    const float4* kr = (const float4*)(ktab + (size_t)tk[m] * 512 + k0);
    float4 z0 = zr[0], z1 = zr[1], k4 = kr[0], k5 = kr[1];
    uint4 u;
    u.x = pkbf(z0.x * k4.x, z0.y * k4.y);
    u.y = pkbf(z0.z * k4.z, z0.w * k4.w);
    u.z = pkbf(z1.x * k5.x, z1.y * k5.y);
    u.w = pkbf(z1.z * k5.z, z1.w * k5.w);
    *(uint4*)&zps[(size_t)chunk * 8] = u;
  }
  __syncthreads();

  // ---- phase 1: H = relu(zp @ W1 + b1).  wave: rows [32wr,32wr+32), cols [96wc,96wc+96) ----
  f32x4 acc[2][6];
#pragma unroll
  for (int mt = 0; mt < 2; ++mt)
#pragma unroll
    for (int j = 0; j < 6; ++j) acc[mt][j] = (f32x4){0.f, 0.f, 0.f, 0.f};

  {
    const short* wb = W1p + ((size_t)(wc * 6) * 64 + lane) * 8;
#pragma unroll 4
    for (int kt = 0; kt < 16; ++kt) {
      bf16x8 a0 = *(bf16x8*)&zps[((kt * 4 + wr * 2 + 0) * 64 + lane) * 8];
      bf16x8 a1 = *(bf16x8*)&zps[((kt * 4 + wr * 2 + 1) * 64 + lane) * 8];
#pragma unroll
      for (int j = 0; j < 6; ++j) {
        bf16x8 bf = *(const bf16x8*)(wb + (size_t)kt * 12288 + j * 512);
        acc[0][j] = __builtin_amdgcn_mfma_f32_16x16x32_bf16(a0, bf, acc[0][j], 0, 0, 0);
        acc[1][j] = __builtin_amdgcn_mfma_f32_16x16x32_bf16(a1, bf, acc[1][j], 0, 0, 0);
      }
    }
  }
  __syncthreads();   // all zps reads done; Hs aliases zps

  // ---- epilogue 1: bias + relu + pack into phase-2 A-fragment layout ----
  {
    short* Hs = zps;
    float bload[6];
#pragma unroll
    for (int j = 0; j < 6; ++j)
      bload[j] = b1[wc * 96 + j * 16 + (lane & 15)];
#pragma unroll
    for (int mt = 0; mt < 2; ++mt) {
#pragma unroll
      for (int j = 0; j < 6; ++j) {
        int c = wc * 96 + j * 16 + (lane & 15);
        int lane2hi = ((c >> 3) & 3) << 4;
        int ktp = (c >> 5) * 4;          // 4 mt-groups per kt in phase-2 layout
        int jj = c & 7;
        // consecutive r -> (m&15) steps by 1 -> address steps by 8 shorts
        int mbase = wr * 32 + mt * 16 + (lane >> 4) * 4;
        int a0 = ((ktp + (mbase >> 4)) * 64 + ((mbase & 15) | lane2hi)) * 8 + jj;
        float v0 = fmaxf(acc[mt][j][0] + bload[j], 0.f);
        float v1 = fmaxf(acc[mt][j][1] + bload[j], 0.f);
        float v2 = fmaxf(acc[mt][j][2] + bload[j], 0.f);
        float v3 = fmaxf(acc[mt][j][3] + bload[j], 0.f);
        unsigned p01 = pkbf(v0, v1);
        unsigned p23 = pkbf(v2, v3);
        Hs[a0 +  0] = (short)(p01 & 0xFFFFu);
        Hs[a0 +  8] = (short)(p01 >> 16);
        Hs[a0 + 16] = (short)(p23 & 0xFFFFu);
        Hs[a0 + 24] = (short)(p23 >> 16);
      }
    }
  }
  __syncthreads();

  // ---- phase 2: x = H @ W2 + b2.  wave: rows [32wr,32wr+32), cols [64wc,64wc+64) ----
  f32x4 acc2[2][4];
#pragma unroll
  for (int mt = 0; mt < 2; ++mt)
#pragma unroll
    for (int j = 0; j < 4; ++j) acc2[mt][j] = (f32x4){0.f, 0.f, 0.f, 0.f};

  {
    const short* Hs = zps;
    const short* wb = W2p + ((size_t)(wc * 4) * 64 + lane) * 8;
#pragma unroll 4
    for (int kt = 0; kt < 12; ++kt) {
      bf16x8 a0 = *(const bf16x8*)&Hs[((kt * 4 + wr * 2 + 0) * 64 + lane) * 8];
      bf16x8 a1 = *(const bf16x8*)&Hs[((kt * 4 + wr * 2 + 1) * 64 + lane) * 8];
#pragma unroll
      for (int j = 0; j < 4; ++j) {
        bf16x8 bf = *(const bf16x8*)(wb + (size_t)kt * 8192 + j * 512);
        acc2[0][j] = __builtin_amdgcn_mfma_f32_16x16x32_bf16(a0, bf, acc2[0][j], 0, 0, 0);
        acc2[1][j] = __builtin_amdgcn_mfma_f32_16x16x32_bf16(a1, bf, acc2[1][j], 0, 0, 0);
      }
    }
  }

  // ---- epilogue 2: bias + store ----
  {
    float bload[4];
#pragma unroll
    for (int j = 0; j < 4; ++j)
      bload[j] = b2[wc * 64 + j * 16 + (lane & 15)];
#pragma unroll
    for (int mt = 0; mt < 2; ++mt) {
#pragma unroll
      for (int r = 0; r < 4; ++r) {
        int t = t0 + wr * 32 + mt * 16 + (lane >> 4) * 4 + r;
        if (t < T) {
#pragma unroll
          for (int j = 0; j < 4; ++j) {
            int c = wc * 64 + j * 16 + (lane & 15);
            out[(size_t)t * 256 + c] = acc2[mt][j][r] + bload[j];
          }
        }
      }
    }
  }
}

// ---------------------------------------------------------------------------
extern "C" void kernel_launch(void* const* d_in, const int* in_sizes, int n_in,
                              void* d_out, int out_size, void* d_ws, size_t ws_size,
                              hipStream_t stream)
{
  const float* z      = (const float*)d_in[0];
  const float* keyW1  = (const float*)d_in[1];
  const float* keyb1  = (const float*)d_in[2];
  const float* keyg1  = (const float*)d_in[3];
  const float* keybe1 = (const float*)d_in[4];
  const float* keyW2  = (const float*)d_in[5];
  const float* keyb2  = (const float*)d_in[6];
  const float* decW1  = (const float*)d_in[7];
  const float* decb1  = (const float*)d_in[8];
  const float* decW2  = (const float*)d_in[9];
  const float* decb2  = (const float*)d_in[10];
  const float* spW1   = (const float*)d_in[11];
  const float* spb1   = (const float*)d_in[12];
  const float* spg1   = (const float*)d_in[13];
  const float* spbe1  = (const float*)d_in[14];
  const float* spW2   = (const float*)d_in[15];
  const float* spb2   = (const float*)d_in[16];

  const int T = out_size / (DIM + 1);   // out = x[T,256] ++ batch[T]

  char* ws = (char*)d_ws;
  int*   n_arr  = (int*)(ws);                 // 32768 ints
  int*   starts = (int*)(ws + 131072);        // 32769 ints
  float* ktab   = (float*)(ws + 262160);      // 17*512 f32
  short* W1p    = (short*)(ws + 296976);      // 512*384 bf16 = 393216 B
  short* W2p    = (short*)(ws + 690192);      // 384*256 bf16 = 196608 B
  int*   bi     = (int*)(ws + 886800);        // T ints
  size_t kioff  = 886800 + (((size_t)T * 4 + 15) / 16) * 16;
  int*   ki     = (int*)(ws + kioff);         // T ints

  float* outF = (float*)d_out;

  sizepred_kernel<<<B_N / 16, 320, 0, stream>>>(z, spW1, spb1, spg1, spbe1, spW2, spb2, n_arr);
  pack_kernel<<<576, 64, 0, stream>>>(decW1, decW2, W1p, W2p);
  scan_kernel<<<1, 1024, 0, stream>>>(n_arr, starts);
  keys_kernel<<<MAXN, 320, 0, stream>>>(keyW1, keyb1, keyg1, keybe1, keyW2, keyb2, ktab);
  scatter_kernel<<<B_N / 256, 256, 0, stream>>>(n_arr, starts, bi, ki, outF, T);
  if (T > 0)
    decoder_kernel<<<(T + 63) / 64, 512, 0, stream>>>(z, ktab, W1p, decb1, W2p, decb2, bi, ki, outF, T);
}

// Round 12
// 1117.601 us; speedup vs baseline: 1.0406x; 1.0406x over previous
//
#include <hip/hip_runtime.h>
#include <hip/hip_bf16.h>

#define B_N   32768
#define HID   512
#define DIM   256
#define MAXN  17
#define SM    264   // SP_MID == KEY_MID
#define DM    384   // DEC_MID

typedef __attribute__((ext_vector_type(8))) short bf16x8;
typedef __attribute__((ext_vector_type(4))) float f32x4;

#define AS1 __attribute__((address_space(1)))
#define AS3 __attribute__((address_space(3)))

static __device__ __forceinline__ unsigned short f2bf(float x) {
  union { float f; unsigned u; } v; v.f = x;
  unsigned r = (v.u + 0x7FFFu + ((v.u >> 16) & 1u)) >> 16;   // RNE
  return (unsigned short)r;
}

// Packed RNE f32x2 -> bf16x2 (v_cvt_pk_bf16_f32); bit-identical to f2bf pair.
static __device__ __forceinline__ unsigned pkbf(float a, float b) {
  __hip_bfloat162 h = __float22bfloat162_rn(float2{a, b});
  union { __hip_bfloat162 h; unsigned u; } cv; cv.h = h;
  return cv.u;
}

// ---------------------------------------------------------------------------
// Stage 1: size_pred MLP + argmax.  16 samples / workgroup, 320 threads.
// v6 (verbatim from passing round-6): all staging via global_load_lds.
// MUST stay fp32: argmax flips would corrupt the ragged layout.
// ---------------------------------------------------------------------------
__global__ __launch_bounds__(320, 3) void sizepred_kernel(
    const float* __restrict__ z,  const float* __restrict__ W1,
    const float* __restrict__ b1, const float* __restrict__ g1,
    const float* __restrict__ be1, const float* __restrict__ W2,
    const float* __restrict__ b2, int* __restrict__ n_out)
{
  // pool: zs[16][516] (33024 B, aliased by us[16][268]) + wbuf[2] (8448 B each)
  __shared__ __align__(16) char smem[33024 + 2 * 8448];
  float* zs  = (float*)smem;
  float* us  = (float*)smem;
  float* wb0 = (float*)(smem + 33024);
  float* wb1 = (float*)(smem + 33024 + 8448);
  __shared__ float lnm[16], lnr[16];
  __shared__ float log17[16 * 17];

  const int tid = threadIdx.x;
  const int b0  = blockIdx.x * 16;
  const int wv  = tid >> 6;     // wave 0..4
  const int ln  = tid & 63;

  const bool act = tid < 264;
  const int  s0  = (tid / 66) * 4;
  const int  j0  = (tid % 66) * 4;

  float acc[4][4];
#pragma unroll
  for (int i = 0; i < 4; ++i)
#pragma unroll
    for (int q = 0; q < 4; ++q) acc[i][q] = 0.f;

  // ---- stage zs (once): 16 rows x 512 f = 32 slices of 64 float4.
  for (int s = wv; s < 32; s += 5) {
    int r = s >> 1, sl = s & 1;
    const float* gp = z + (size_t)(b0 + r) * 512 + sl * 256 + ln * 4;
    __builtin_amdgcn_global_load_lds(
        (const AS1 unsigned*)gp,
        (AS3 unsigned*)(zs + r * 516 + sl * 256), 16, 0, 0);
  }
  // ---- stage W chunk 0 into wb0: 528 f4 = 8 full slices + 64-float tail ----
  {
    const float* gc = W1;
    const float* gp1 = gc + (size_t)(wv * 64 + ln) * 4;
    __builtin_amdgcn_global_load_lds(
        (const AS1 unsigned*)gp1, (AS3 unsigned*)(wb0 + wv * 256), 16, 0, 0);
    if (wv < 3) {
      const float* gp2 = gc + (size_t)((wv + 5) * 64 + ln) * 4;
      __builtin_amdgcn_global_load_lds(
          (const AS1 unsigned*)gp2, (AS3 unsigned*)(wb0 + (wv + 5) * 256), 16, 0, 0);
    } else if (wv == 3) {
      const float* gp2 = gc + 2048 + ln;     // floats 2048..2111 (width 4)
      __builtin_amdgcn_global_load_lds(
          (const AS1 unsigned*)gp2, (AS3 unsigned*)(wb0 + 2048), 4, 0, 0);
    }
  }
  __syncthreads();

  // ---- main GEMM: 64 chunks of 8 k, double-buffered W1 via global_load_lds ----
  float* cw = wb0;
  float* nw = wb1;
#pragma unroll 1
  for (int ch = 0; ch < 64; ++ch) {
    if (ch + 1 < 64) {
      const float* gc = W1 + (size_t)(ch + 1) * 2112;   // 8*264
      const float* gp1 = gc + (size_t)(wv * 64 + ln) * 4;
      __builtin_amdgcn_global_load_lds(
          (const AS1 unsigned*)gp1, (AS3 unsigned*)(nw + wv * 256), 16, 0, 0);
      if (wv < 3) {
        const float* gp2 = gc + (size_t)((wv + 5) * 64 + ln) * 4;
        __builtin_amdgcn_global_load_lds(
            (const AS1 unsigned*)gp2, (AS3 unsigned*)(nw + (wv + 5) * 256), 16, 0, 0);
      } else if (wv == 3) {
        const float* gp2 = gc + 2048 + ln;
        __builtin_amdgcn_global_load_lds(
            (const AS1 unsigned*)gp2, (AS3 unsigned*)(nw + 2048), 4, 0, 0);
      }
    }
    if (act) {
      const int zb = ch * 8;
#pragma unroll
      for (int u = 0; u < 2; ++u) {
        float4 za0 = *(const float4*)&zs[(s0 + 0) * 516 + zb + u * 4];
        float4 za1 = *(const float4*)&zs[(s0 + 1) * 516 + zb + u * 4];
        float4 za2 = *(const float4*)&zs[(s0 + 2) * 516 + zb + u * 4];
        float4 za3 = *(const float4*)&zs[(s0 + 3) * 516 + zb + u * 4];
#pragma unroll
        for (int e = 0; e < 4; ++e) {
          float4 w = *(const float4*)&cw[(u * 4 + e) * 264 + j0];
          float a0 = (e == 0) ? za0.x : (e == 1) ? za0.y : (e == 2) ? za0.z : za0.w;
          float a1 = (e == 0) ? za1.x : (e == 1) ? za1.y : (e == 2) ? za1.z : za1.w;
          float a2 = (e == 0) ? za2.x : (e == 1) ? za2.y : (e == 2) ? za2.z : za2.w;
          float a3 = (e == 0) ? za3.x : (e == 1) ? za3.y : (e == 2) ? za3.z : za3.w;
          acc[0][0] += a0 * w.x; acc[0][1] += a0 * w.y; acc[0][2] += a0 * w.z; acc[0][3] += a0 * w.w;
          acc[1][0] += a1 * w.x; acc[1][1] += a1 * w.y; acc[1][2] += a1 * w.z; acc[1][3] += a1 * w.w;
          acc[2][0] += a2 * w.x; acc[2][1] += a2 * w.y; acc[2][2] += a2 * w.z; acc[2][3] += a2 * w.w;
          acc[3][0] += a3 * w.x; acc[3][1] += a3 * w.y; acc[3][2] += a3 * w.z; acc[3][3] += a3 * w.w;
        }
      }
    }
    float* t = cw; cw = nw; nw = t;
    __syncthreads();
  }

  // ---- bias into registers (masked), uniform barrier, masked store ----
  float4 o0, o1, o2, o3;
  if (act) {
    float4 bb = *(const float4*)&b1[j0];
    o0.x = acc[0][0] + bb.x; o0.y = acc[0][1] + bb.y; o0.z = acc[0][2] + bb.z; o0.w = acc[0][3] + bb.w;
    o1.x = acc[1][0] + bb.x; o1.y = acc[1][1] + bb.y; o1.z = acc[1][2] + bb.z; o1.w = acc[1][3] + bb.w;
    o2.x = acc[2][0] + bb.x; o2.y = acc[2][1] + bb.y; o2.z = acc[2][2] + bb.z; o2.w = acc[2][3] + bb.w;
    o3.x = acc[3][0] + bb.x; o3.y = acc[3][1] + bb.y; o3.z = acc[3][2] + bb.z; o3.w = acc[3][3] + bb.w;
  }
  __syncthreads();   // zs -> us handoff (uniform: all zs reads done above)
  if (act) {
    *(float4*)&us[(s0 + 0) * 268 + j0] = o0;
    *(float4*)&us[(s0 + 1) * 268 + j0] = o1;
    *(float4*)&us[(s0 + 2) * 268 + j0] = o2;
    *(float4*)&us[(s0 + 3) * 268 + j0] = o3;
  }
  __syncthreads();

  // LN stats: serial per sample — EXACT summation order of verified baseline.
  if (tid < 16) {
    float s = 0.f, q = 0.f;
    for (int j = 0; j < 264; ++j) { float v = us[tid * 268 + j]; s += v; q += v * v; }
    float m   = s / 264.f;
    float var = q / 264.f - m * m;
    lnm[tid] = m;
    lnr[tid] = 1.f / sqrtf(var + 1e-5f);
  }
  __syncthreads();

  for (int idx = tid; idx < 16 * 264; idx += 320) {
    int s = idx / 264, j = idx - s * 264;
    float v = (us[s * 268 + j] - lnm[s]) * lnr[s] * g1[j] + be1[j];
    us[s * 268 + j] = fmaxf(v, 0.f);
  }
  __syncthreads();

  if (tid < 272) {
    int s = tid / 17, jj = tid - s * 17;
    float a = b2[jj];
    const float* up = &us[s * 268];
#pragma unroll 4
    for (int c = 0; c < 264; c += 4) {
      float4 u = *(const float4*)(up + c);
      a += u.x * W2[(c + 0) * 17 + jj];
      a += u.y * W2[(c + 1) * 17 + jj];
      a += u.z * W2[(c + 2) * 17 + jj];
      a += u.w * W2[(c + 3) * 17 + jj];
    }
    log17[tid] = a;
  }
  __syncthreads();

  if (tid < 16) {
    int best = 0; float bv = log17[tid * 17];
    for (int jj = 1; jj < 17; ++jj) {
      float v = log17[tid * 17 + jj];
      if (v > bv) { bv = v; best = jj; }
    }
    n_out[b0 + tid] = best;
  }
}

// ---------------------------------------------------------------------------
// Stage 2: exclusive prefix sum of n[32768] -> starts[32769]. One block.
// ---------------------------------------------------------------------------
__global__ __launch_bounds__(1024) void scan_kernel(const int* __restrict__ n,
                                                    int* __restrict__ starts)
{
  __shared__ int part[1024];
  const int tid  = threadIdx.x;
  const int base = tid * 32;
  int loc[32];
  int s = 0;
#pragma unroll
  for (int i = 0; i < 8; ++i) {
    int4 v = ((const int4*)(n + base))[i];
    loc[i * 4 + 0] = v.x; loc[i * 4 + 1] = v.y;
    loc[i * 4 + 2] = v.z; loc[i * 4 + 3] = v.w;
    s += v.x + v.y + v.z + v.w;
  }
  part[tid] = s;
  __syncthreads();
  for (int off = 1; off < 1024; off <<= 1) {
    int v   = part[tid];
    int add = (tid >= off) ? part[tid - off] : 0;
    __syncthreads();
    part[tid] = v + add;
    __syncthreads();
  }
  int run = part[tid] - s;
#pragma unroll
  for (int i = 0; i < 8; ++i) {
    int4 w;
    w.x = run; run += loc[i * 4 + 0];
    w.y = run; run += loc[i * 4 + 1];
    w.z = run; run += loc[i * 4 + 2];
    w.w = run; run += loc[i * 4 + 3];
    ((int4*)(starts + base))[i] = w;
  }
  if (tid == 1023) starts[B_N] = run;
}

// ---------------------------------------------------------------------------
// Stage 3: scatter ragged indices + write batch output (as float)
// ---------------------------------------------------------------------------
__global__ __launch_bounds__(256) void scatter_kernel(
    const int* __restrict__ n, const int* __restrict__ starts,
    int* __restrict__ bi, int* __restrict__ ki, float* __restrict__ out, int T)
{
  int b = blockIdx.x * 256 + threadIdx.x;
  if (b >= B_N) return;
  int st = starts[b], nn = n[b];
  float* ob = out + (size_t)T * DIM;
  for (int k = 0; k < nn; ++k) {
    bi[st + k] = b;
    ki[st + k] = k;
    ob[st + k] = (float)b;
  }
}

// ---------------------------------------------------------------------------
// Stage 4: keys table [17][512]
// ---------------------------------------------------------------------------
__global__ __launch_bounds__(320) void keys_kernel(
    const float* __restrict__ W1, const float* __restrict__ b1,
    const float* __restrict__ g1, const float* __restrict__ be1,
    const float* __restrict__ W2, const float* __restrict__ b2,
    float* __restrict__ ktab)
{
  __shared__ float hs[264];
  __shared__ float mr[2];
  const int kk = blockIdx.x, tid = threadIdx.x;
  if (tid < 264) hs[tid] = W1[kk * 264 + tid] + b1[tid];
  __syncthreads();
  if (tid == 0) {
    float s = 0.f, q = 0.f;
    for (int j = 0; j < 264; ++j) { float v = hs[j]; s += v; q += v * v; }
    float m = s / 264.f;
    mr[0] = m;
    mr[1] = 1.f / sqrtf(q / 264.f - m * m + 1e-5f);
  }
  __syncthreads();
  if (tid < 264) hs[tid] = fmaxf((hs[tid] - mr[0]) * mr[1] * g1[tid] + be1[tid], 0.f);
  __syncthreads();
  for (int c = tid; c < 512; c += 320) {
    float a = b2[c];
    for (int j = 0; j < 264; ++j) a += hs[j] * W2[j * 512 + c];
    ktab[kk * 512 + c] = a;
  }
}

// ---------------------------------------------------------------------------
// Stage 4b: pack dec_W1/dec_W2 into bf16 MFMA B-fragment layout.
// Chunk (kt, nt, lane): 8 bf16 = W[kt*32 + (lane>>4)*8 + j][nt*16 + (lane&15)]
// W1p: 16 kt x 24 nt ; W2p: 12 kt x 16 nt.  grid 576 x 64.
// ---------------------------------------------------------------------------
__global__ __launch_bounds__(64) void pack_kernel(
    const float* __restrict__ W1, const float* __restrict__ W2,
    short* __restrict__ W1p, short* __restrict__ W2p)
{
  const int g = blockIdx.x, l = threadIdx.x;
  const float* W; int nt, kt, N;
  if (g < 384) { W = W1; kt = g / 24; nt = g % 24; N = 384; }
  else         { W = W2; int gg = g - 384; kt = gg / 16; nt = gg % 16; N = 256; }
  const int krow = kt * 32 + ((l >> 4) << 3);
  const int col  = nt * 16 + (l & 15);
  short v[8];
#pragma unroll
  for (int j = 0; j < 8; ++j)
    v[j] = (short)f2bf(W[(size_t)(krow + j) * N + col]);
  short* d = (g < 384) ? (W1p + ((size_t)g * 64 + l) * 8)
                       : (W2p + ((size_t)(g - 384) * 64 + l) * 8);
  *(bf16x8*)d = *(bf16x8*)v;
}

// ---------------------------------------------------------------------------
// Stage 5: MFMA decoder v5: 32 rows / block (the better-measured 452us base,
// 4 blocks/CU) + EXPLICIT kt-level B-fragment register double-buffer in both
// MFMA phases.  Round-11 counters refuted the L2-BW theory (halved traffic,
// same dur): kernel is latency-bound at VGPR=52 (compiler keeps ~1 kt of B
// in flight; each kt exposes ~250cyc L2 latency vs 60cyc MFMA issue).
// Prefetch distance 1 (named regs, compile-time rotation) hides the load
// under the previous kt's MFMA block.  Budget ~120 VGPR < 128 cap of
// __launch_bounds__(256,4).
// ---------------------------------------------------------------------------
__global__ __launch_bounds__(256, 4) void decoder_kernel(
    const float* __restrict__ z,  const float* __restrict__ ktab,
    const short* __restrict__ W1p, const float* __restrict__ b1,
    const short* __restrict__ W2p, const float* __restrict__ b2,
    const int* __restrict__ bi,   const int* __restrict__ ki,
    float* __restrict__ out, int T)
{
  // zps: 2 mt x 16 kt x 64 lanes x 8 bf16 = 32 KB.  Hs (24 KB) aliases it.
  __shared__ __align__(16) short zps[16384];
  __shared__ int tb[32], tk[32];

  const int tid  = threadIdx.x;
  const int wave = tid >> 6;
  const int lane = tid & 63;
  const int t0   = blockIdx.x * 32;

  if (tid < 32) {
    int t = t0 + tid;
    tb[tid] = (t < T) ? bi[t] : 0;
    tk[tid] = (t < T) ? ki[t] : 0;
  }
  __syncthreads();

  // ---- stage zp = z[b]*ktab[k] into A-fragment layout ----
  // chunk = (kt*2 + mt)*64 + lane ; element j = zp[mt*16+(lane&15)][kt*32+(lane>>4)*8+j]
#pragma unroll
  for (int it = 0; it < 8; ++it) {
    int chunk = tid + it * 256;
    int l  = chunk & 63;
    int mt = (chunk >> 6) & 1;
    int kt = chunk >> 7;
    int m  = mt * 16 + (l & 15);
    int k0 = kt * 32 + ((l >> 4) << 3);
    const float4* zr = (const float4*)(z    + (size_t)tb[m] * 512 + k0);
    const float4* kr = (const float4*)(ktab + (size_t)tk[m] * 512 + k0);
    float4 z0 = zr[0], z1 = zr[1], k4 = kr[0], k5 = kr[1];
    uint4 u;
    u.x = pkbf(z0.x * k4.x, z0.y * k4.y);
    u.y = pkbf(z0.z * k4.z, z0.w * k4.w);
    u.z = pkbf(z1.x * k5.x, z1.y * k5.y);
    u.w = pkbf(z1.z * k5.z, z1.w * k5.w);
    *(uint4*)&zps[(size_t)chunk * 8] = u;
  }
  __syncthreads();

  // ---- phase 1: H = relu(zp @ W1 + b1).  wave covers cols [96w, 96w+96) ----
  f32x4 acc[2][6];
#pragma unroll
  for (int mt = 0; mt < 2; ++mt)
#pragma unroll
    for (int j = 0; j < 6; ++j) acc[mt][j] = (f32x4){0.f, 0.f, 0.f, 0.f};

  {
    const short* wb = W1p + ((size_t)(wave * 6) * 64 + lane) * 8;
    // prologue: B-fragments for kt=0
    bf16x8 c0 = *(const bf16x8*)(wb + 0);
    bf16x8 c1 = *(const bf16x8*)(wb + 512);
    bf16x8 c2 = *(const bf16x8*)(wb + 1024);
    bf16x8 c3 = *(const bf16x8*)(wb + 1536);
    bf16x8 c4 = *(const bf16x8*)(wb + 2048);
    bf16x8 c5 = *(const bf16x8*)(wb + 2560);
#pragma unroll
    for (int kt = 0; kt < 16; ++kt) {
      bf16x8 n0, n1, n2, n3, n4, n5;
      if (kt + 1 < 16) {
        const short* wn = wb + (size_t)(kt + 1) * 12288;
        n0 = *(const bf16x8*)(wn + 0);
        n1 = *(const bf16x8*)(wn + 512);
        n2 = *(const bf16x8*)(wn + 1024);
        n3 = *(const bf16x8*)(wn + 1536);
        n4 = *(const bf16x8*)(wn + 2048);
        n5 = *(const bf16x8*)(wn + 2560);
      }
      bf16x8 a0 = *(bf16x8*)&zps[((kt * 2 + 0) * 64 + lane) * 8];
      bf16x8 a1 = *(bf16x8*)&zps[((kt * 2 + 1) * 64 + lane) * 8];
      acc[0][0] = __builtin_amdgcn_mfma_f32_16x16x32_bf16(a0, c0, acc[0][0], 0, 0, 0);
      acc[1][0] = __builtin_amdgcn_mfma_f32_16x16x32_bf16(a1, c0, acc[1][0], 0, 0, 0);
      acc[0][1] = __builtin_amdgcn_mfma_f32_16x16x32_bf16(a0, c1, acc[0][1], 0, 0, 0);
      acc[1][1] = __builtin_amdgcn_mfma_f32_16x16x32_bf16(a1, c1, acc[1][1], 0, 0, 0);
      acc[0][2] = __builtin_amdgcn_mfma_f32_16x16x32_bf16(a0, c2, acc[0][2], 0, 0, 0);
      acc[1][2] = __builtin_amdgcn_mfma_f32_16x16x32_bf16(a1, c2, acc[1][2], 0, 0, 0);
      acc[0][3] = __builtin_amdgcn_mfma_f32_16x16x32_bf16(a0, c3, acc[0][3], 0, 0, 0);
      acc[1][3] = __builtin_amdgcn_mfma_f32_16x16x32_bf16(a1, c3, acc[1][3], 0, 0, 0);
      acc[0][4] = __builtin_amdgcn_mfma_f32_16x16x32_bf16(a0, c4, acc[0][4], 0, 0, 0);
      acc[1][4] = __builtin_amdgcn_mfma_f32_16x16x32_bf16(a1, c4, acc[1][4], 0, 0, 0);
      acc[0][5] = __builtin_amdgcn_mfma_f32_16x16x32_bf16(a0, c5, acc[0][5], 0, 0, 0);
      acc[1][5] = __builtin_amdgcn_mfma_f32_16x16x32_bf16(a1, c5, acc[1][5], 0, 0, 0);
      if (kt + 1 < 16) {
        c0 = n0; c1 = n1; c2 = n2; c3 = n3; c4 = n4; c5 = n5;
      }
    }
  }
  __syncthreads();   // all zps reads done; Hs aliases zps

  // ---- epilogue 1: bias + relu + pack into phase-2 A-fragment layout ----
  {
    short* Hs = zps;
    float bload[6];
#pragma unroll
    for (int j = 0; j < 6; ++j)
      bload[j] = b1[wave * 96 + j * 16 + (lane & 15)];
#pragma unroll
    for (int mt = 0; mt < 2; ++mt) {
#pragma unroll
      for (int j = 0; j < 6; ++j) {
        int c = wave * 96 + j * 16 + (lane & 15);
        int lane2hi = ((c >> 3) & 3) << 4;
        int koff = (c >> 5) * 2;
        int jj = c & 7;
        // consecutive r -> (m&15) steps by 1 -> address steps by 8 shorts
        int mbase = mt * 16 + (lane >> 4) * 4;
        int a0 = ((koff + (mbase >> 4)) * 64 + ((mbase & 15) | lane2hi)) * 8 + jj;
        float v0 = fmaxf(acc[mt][j][0] + bload[j], 0.f);
        float v1 = fmaxf(acc[mt][j][1] + bload[j], 0.f);
        float v2 = fmaxf(acc[mt][j][2] + bload[j], 0.f);
        float v3 = fmaxf(acc[mt][j][3] + bload[j], 0.f);
        unsigned p01 = pkbf(v0, v1);
        unsigned p23 = pkbf(v2, v3);
        Hs[a0 +  0] = (short)(p01 & 0xFFFFu);
        Hs[a0 +  8] = (short)(p01 >> 16);
        Hs[a0 + 16] = (short)(p23 & 0xFFFFu);
        Hs[a0 + 24] = (short)(p23 >> 16);
      }
    }
  }
  __syncthreads();

  // ---- phase 2: x = H @ W2 + b2.  wave covers cols [64w, 64w+64) ----
  f32x4 acc2[2][4];
#pragma unroll
  for (int mt = 0; mt < 2; ++mt)
#pragma unroll
    for (int j = 0; j < 4; ++j) acc2[mt][j] = (f32x4){0.f, 0.f, 0.f, 0.f};

  {
    const short* Hs = zps;
    const short* wb = W2p + ((size_t)(wave * 4) * 64 + lane) * 8;
    bf16x8 c0 = *(const bf16x8*)(wb + 0);
    bf16x8 c1 = *(const bf16x8*)(wb + 512);
    bf16x8 c2 = *(const bf16x8*)(wb + 1024);
    bf16x8 c3 = *(const bf16x8*)(wb + 1536);
#pragma unroll
    for (int kt = 0; kt < 12; ++kt) {
      bf16x8 n0, n1, n2, n3;
      if (kt + 1 < 12) {
        const short* wn = wb + (size_t)(kt + 1) * 8192;
        n0 = *(const bf16x8*)(wn + 0);
        n1 = *(const bf16x8*)(wn + 512);
        n2 = *(const bf16x8*)(wn + 1024);
        n3 = *(const bf16x8*)(wn + 1536);
      }
      bf16x8 a0 = *(const bf16x8*)&Hs[((kt * 2 + 0) * 64 + lane) * 8];
      bf16x8 a1 = *(const bf16x8*)&Hs[((kt * 2 + 1) * 64 + lane) * 8];
      acc2[0][0] = __builtin_amdgcn_mfma_f32_16x16x32_bf16(a0, c0, acc2[0][0], 0, 0, 0);
      acc2[1][0] = __builtin_amdgcn_mfma_f32_16x16x32_bf16(a1, c0, acc2[1][0], 0, 0, 0);
      acc2[0][1] = __builtin_amdgcn_mfma_f32_16x16x32_bf16(a0, c1, acc2[0][1], 0, 0, 0);
      acc2[1][1] = __builtin_amdgcn_mfma_f32_16x16x32_bf16(a1, c1, acc2[1][1], 0, 0, 0);
      acc2[0][2] = __builtin_amdgcn_mfma_f32_16x16x32_bf16(a0, c2, acc2[0][2], 0, 0, 0);
      acc2[1][2] = __builtin_amdgcn_mfma_f32_16x16x32_bf16(a1, c2, acc2[1][2], 0, 0, 0);
      acc2[0][3] = __builtin_amdgcn_mfma_f32_16x16x32_bf16(a0, c3, acc2[0][3], 0, 0, 0);
      acc2[1][3] = __builtin_amdgcn_mfma_f32_16x16x32_bf16(a1, c3, acc2[1][3], 0, 0, 0);
      if (kt + 1 < 12) {
        c0 = n0; c1 = n1; c2 = n2; c3 = n3;
      }
    }
  }

  // ---- epilogue 2: bias + store ----
  {
    float bload[4];
#pragma unroll
    for (int j = 0; j < 4; ++j)
      bload[j] = b2[wave * 64 + j * 16 + (lane & 15)];
#pragma unroll
    for (int mt = 0; mt < 2; ++mt) {
#pragma unroll
      for (int r = 0; r < 4; ++r) {
        int t = t0 + mt * 16 + (lane >> 4) * 4 + r;
        if (t < T) {
#pragma unroll
          for (int j = 0; j < 4; ++j) {
            int c = wave * 64 + j * 16 + (lane & 15);
            out[(size_t)t * 256 + c] = acc2[mt][j][r] + bload[j];
          }
        }
      }
    }
  }
}

// ---------------------------------------------------------------------------
extern "C" void kernel_launch(void* const* d_in, const int* in_sizes, int n_in,
                              void* d_out, int out_size, void* d_ws, size_t ws_size,
                              hipStream_t stream)
{
  const float* z      = (const float*)d_in[0];
  const float* keyW1  = (const float*)d_in[1];
  const float* keyb1  = (const float*)d_in[2];
  const float* keyg1  = (const float*)d_in[3];
  const float* keybe1 = (const float*)d_in[4];
  const float* keyW2  = (const float*)d_in[5];
  const float* keyb2  = (const float*)d_in[6];
  const float* decW1  = (const float*)d_in[7];
  const float* decb1  = (const float*)d_in[8];
  const float* decW2  = (const float*)d_in[9];
  const float* decb2  = (const float*)d_in[10];
  const float* spW1   = (const float*)d_in[11];
  const float* spb1   = (const float*)d_in[12];
  const float* spg1   = (const float*)d_in[13];
  const float* spbe1  = (const float*)d_in[14];
  const float* spW2   = (const float*)d_in[15];
  const float* spb2   = (const float*)d_in[16];

  const int T = out_size / (DIM + 1);   // out = x[T,256] ++ batch[T]

  char* ws = (char*)d_ws;
  int*   n_arr  = (int*)(ws);                 // 32768 ints
  int*   starts = (int*)(ws + 131072);        // 32769 ints
  float* ktab   = (float*)(ws + 262160);      // 17*512 f32
  short* W1p    = (short*)(ws + 296976);      // 512*384 bf16 = 393216 B
  short* W2p    = (short*)(ws + 690192);      // 384*256 bf16 = 196608 B
  int*   bi     = (int*)(ws + 886800);        // T ints
  size_t kioff  = 886800 + (((size_t)T * 4 + 15) / 16) * 16;
  int*   ki     = (int*)(ws + kioff);         // T ints

  float* outF = (float*)d_out;

  sizepred_kernel<<<B_N / 16, 320, 0, stream>>>(z, spW1, spb1, spg1, spbe1, spW2, spb2, n_arr);
  pack_kernel<<<576, 64, 0, stream>>>(decW1, decW2, W1p, W2p);
  scan_kernel<<<1, 1024, 0, stream>>>(n_arr, starts);
  keys_kernel<<<MAXN, 320, 0, stream>>>(keyW1, keyb1, keyg1, keybe1, keyW2, keyb2, ktab);
  scatter_kernel<<<B_N / 256, 256, 0, stream>>>(n_arr, starts, bi, ki, outF, T);
  if (T > 0)
    decoder_kernel<<<(T + 31) / 32, 256, 0, stream>>>(z, ktab, W1p, decb1, W2p, decb2, bi, ki, outF, T);
}